// Round 1
// baseline (495.487 us; speedup 1.0000x reference)
//
#include <hip/hip_runtime.h>
#include <math.h>

#define N_TRAIN 1000000
#define KSEL 32
#define GRID1 2048
#define GRID2 256
#define NBINS 512
#define BINSCALE 16.0f      // bin = (int)(d*16), covers d in [0,32)
#define CAP 512             // max candidates kept (typ. ~40-100 for this data)

// ---------------------------------------------------------------------------
// Kernel 1: distances + softmax-denominator partials + global 512-bin
// distance histogram. 16 lanes per row (16 x float4 = 64 floats); a wave
// covers 4 consecutive rows = 1024 contiguous bytes -> fully coalesced.
// HBM-bound: 256 MB read ~ 40 us; histogram rides along in LDS.
// ---------------------------------------------------------------------------
__global__ __launch_bounds__(256) void dist_kernel(
    const float4* __restrict__ X, const float4* __restrict__ q,
    float* __restrict__ dist, double* __restrict__ blockSums,
    unsigned int* __restrict__ ghist)
{
    __shared__ unsigned int lhist[NBINS];
    __shared__ double wsum[4];

    const int tid = threadIdx.x;
    for (int i = tid; i < NBINS; i += 256) lhist[i] = 0u;
    const int lane16 = tid & 15;
    const float4 q4 = q[lane16];
    __syncthreads();

    const int ngroups = GRID1 * 256 / 16;  // 32768 row-groups
    int group = (blockIdx.x * 256 + tid) >> 4;

    float esum = 0.f;
    for (int row = group; row < N_TRAIN; row += ngroups) {
        float4 v = X[row * 16 + lane16];
        float dx = v.x - q4.x;
        float dy = v.y - q4.y;
        float dz = v.z - q4.z;
        float dw = v.w - q4.w;
        float p = dx * dx + dy * dy + dz * dz + dw * dw;
        p += __shfl_xor(p, 1);
        p += __shfl_xor(p, 2);
        p += __shfl_xor(p, 4);
        p += __shfl_xor(p, 8);
        float d = sqrtf(p);
        if (lane16 == 0) {
            dist[row] = d;
            esum += expf(-d);
            int b = (int)(d * BINSCALE);
            b = b < 0 ? 0 : (b > NBINS - 1 ? NBINS - 1 : b);
            atomicAdd(&lhist[b], 1u);
        }
    }

    // block reduction of esum (also serves as the pre-flush barrier)
    double de = (double)esum;
#pragma unroll
    for (int off = 32; off; off >>= 1) de += __shfl_xor(de, off);
    if ((tid & 63) == 0) wsum[tid >> 6] = de;
    __syncthreads();
    if (tid == 0) blockSums[blockIdx.x] = wsum[0] + wsum[1] + wsum[2] + wsum[3];

    // flush local histogram (skip empty bins to cut global atomics)
    for (int i = tid; i < NBINS; i += 256) {
        unsigned int c = lhist[i];
        if (c) atomicAdd(&ghist[i], c);
    }
}

// ---------------------------------------------------------------------------
// Kernel 2 (fused compact + final): threshold from histogram (wave-parallel
// chunked scan), compact all sub-threshold candidates, then the LAST block
// to finish (device-scope ticket) runs the former final_kernel phase:
// global S, register-resident top-32 over the candidates, weights, y-gather.
// T = smallest bin with cumulative >= 32; every true top-32 element has
// d <= d_32 < (T+1)/16, so the candidate set is exact.
// Key = (float_bits(d) << 32) | idx: positive-float bits are order-monotone,
// so u64 min == (smallest d, then smallest idx) — matches jax top_k tie order.
// ---------------------------------------------------------------------------
__global__ __launch_bounds__(256) void compact_final_kernel(
    const float* __restrict__ dist, const unsigned int* __restrict__ ghist,
    unsigned int* __restrict__ candCount,
    float* __restrict__ cand_v, int* __restrict__ cand_i,
    unsigned int* __restrict__ doneCount,
    const double* __restrict__ blockSums,
    const float* __restrict__ y, float* __restrict__ out)
{
    __shared__ unsigned int hsh[NBINS];
    __shared__ float thr_sh;
    __shared__ unsigned int ticket_sh;
    __shared__ double wsum[4];
    __shared__ double Ssh;
    __shared__ unsigned long long topkey[KSEL];
    __shared__ float tw[KSEL];
    __shared__ int   ti[KSEL];
    __shared__ float accsh[4][64];

    const int tid = threadIdx.x;
    for (int i = tid; i < NBINS; i += 256) hsh[i] = ghist[i];
    __syncthreads();

    // wave 0: chunked 64-lane inclusive scan to find threshold bin.
    // Replaces the old serial tid==0 scan (~120 dependent LDS loads).
    if (tid < 64) {
        unsigned int carry = 0;
        int T = NBINS - 1;
        for (int c = 0; c < NBINS / 64; ++c) {
            unsigned int sc = hsh[c * 64 + tid];
#pragma unroll
            for (int off = 1; off < 64; off <<= 1) {
                unsigned int o = __shfl_up(sc, off);
                if (tid >= off) sc += o;
            }
            unsigned int cum = carry + sc;
            unsigned long long m = __ballot(cum >= KSEL);   // wave-uniform
            if (m != 0ull) { T = c * 64 + (__ffsll(m) - 1); break; }
            carry += __shfl(sc, 63);
        }
        if (tid == 0) thr_sh = (float)(T + 1) / BINSCALE;   // d < thr <=> bin(d) <= T
    }
    __syncthreads();
    const float thr = thr_sh;

    for (int i = blockIdx.x * 256 + tid; i < N_TRAIN; i += GRID2 * 256) {
        float d = dist[i];
        if (d < thr) {
            unsigned int pos = atomicAdd(candCount, 1u);
            if (pos < CAP) { cand_v[pos] = d; cand_i[pos] = i; }
        }
    }

    // ---- last-block ticket: release our candidate stores, take a ticket ----
    __threadfence();          // device-scope release (L2 writeback on gfx950)
    __syncthreads();          // all threads of this block fenced before ticket
    if (tid == 0) ticket_sh = atomicAdd(doneCount, 1u);
    __syncthreads();
    if (ticket_sh != GRID2 - 1) return;
    __threadfence();          // acquire: invalidate stale L1/L2 before reading

    // ---- final phase (last block only) ----

    // reduce the 2048 per-block denominator partials
    double s = 0.0;
    for (int i = tid; i < GRID1; i += 256) s += blockSums[i];
#pragma unroll
    for (int off = 32; off; off >>= 1) s += __shfl_xor(s, off);
    if ((tid & 63) == 0) wsum[tid >> 6] = s;
    __syncthreads();
    if (tid == 0) Ssh = wsum[0] + wsum[1] + wsum[2] + wsum[3];

    // wave 0: extraction entirely in registers, no barriers
    if (tid < 64) {
        int n = (int)(*candCount);
        if (n > CAP) n = CAP;   // practically unreachable for this data
        unsigned long long key[CAP / 64];
#pragma unroll
        for (int s2 = 0; s2 < CAP / 64; ++s2) {
            int i = s2 * 64 + tid;
            if (i < n) {
                unsigned long long vb = (unsigned long long)__float_as_uint(cand_v[i]);
                key[s2] = (vb << 32) | (unsigned int)cand_i[i];
            } else {
                key[s2] = ~0ULL;
            }
        }
        for (int k = 0; k < KSEL; ++k) {
            unsigned long long m = key[0];
#pragma unroll
            for (int s2 = 1; s2 < CAP / 64; ++s2) m = key[s2] < m ? key[s2] : m;
#pragma unroll
            for (int off = 32; off; off >>= 1) {
                unsigned long long o = __shfl_xor(m, off);
                m = o < m ? o : m;
            }
            if (tid == 0) topkey[k] = m;
            bool done = false;
#pragma unroll
            for (int s2 = 0; s2 < CAP / 64; ++s2) {
                if (!done && key[s2] == m) { key[s2] = ~0ULL; done = true; }
            }
        }
    }
    __syncthreads();

    if (tid < KSEL) {
        unsigned long long kk = topkey[tid];
        float d = __uint_as_float((unsigned int)(kk >> 32));
        ti[tid] = (int)(kk & 0xffffffffu);
        tw[tid] = (float)(exp(-(double)d) / Ssh);
    }
    __syncthreads();

    {
        int kg = tid >> 6, dim = tid & 63;
        float acc = 0.f;
#pragma unroll
        for (int kk2 = 0; kk2 < 8; ++kk2) {
            int k = kg * 8 + kk2;
            acc += tw[k] * y[(long)ti[k] * 64 + dim];
        }
        accsh[kg][dim] = acc;
    }
    __syncthreads();
    if (tid < 64) out[tid] = accsh[0][tid] + accsh[1][tid] + accsh[2][tid] + accsh[3][tid];
}

extern "C" void kernel_launch(void* const* d_in, const int* in_sizes, int n_in,
                              void* d_out, int out_size, void* d_ws, size_t ws_size,
                              hipStream_t stream) {
    const float* X = (const float*)d_in[0];   // [1e6, 64]
    const float* y = (const float*)d_in[1];   // [1e6, 64]
    const float* q = (const float*)d_in[2];   // [64]
    float* out = (float*)d_out;               // [64]

    char* w = (char*)d_ws;
    float*        dist      = (float*)w;                      // 4,000,000 B
    double*       bsums     = (double*)(w + 4000000);         //    16,384 B
    unsigned int* ghist     = (unsigned int*)(w + 4016384);   //     2,048 B
    unsigned int* candCount = (unsigned int*)(w + 4018432);   //         4 B
    unsigned int* doneCount = (unsigned int*)(w + 4018436);   //         4 B
    float*        cand_v    = (float*)(w + 4018440);          //     2,048 B
    int*          cand_i    = (int*)(w + 4020488);            //     2,048 B

    // zero histogram + candidate counter + ticket counter (contiguous 2056 B)
    hipMemsetAsync(ghist, 0, 2056, stream);

    dist_kernel<<<GRID1, 256, 0, stream>>>((const float4*)X, (const float4*)q,
                                           dist, bsums, ghist);
    compact_final_kernel<<<GRID2, 256, 0, stream>>>(dist, ghist, candCount,
                                                    cand_v, cand_i, doneCount,
                                                    bsums, y, out);
}

// Round 2
// 480.623 us; speedup vs baseline: 1.0309x; 1.0309x over previous
//
#include <hip/hip_runtime.h>
#include <math.h>

#define N_TRAIN 1000000
#define KSEL 32
#define GRID1 2048
#define GRID2 256
#define NBINS 512
#define BINSCALE 16.0f      // bin = (int)(d*16), covers d in [0,32)
#define CAP 512             // max candidates kept (typ. ~40-100 for this data)

// ---------------------------------------------------------------------------
// Kernel 1: distances + softmax-denominator partials + global 512-bin
// distance histogram. 16 lanes per row (16 x float4 = 64 floats); a wave
// covers 4 consecutive rows = 1024 contiguous bytes -> fully coalesced.
// HBM-bound: 256 MB read ~ 40 us; histogram rides along in LDS.
// ---------------------------------------------------------------------------
__global__ __launch_bounds__(256) void dist_kernel(
    const float4* __restrict__ X, const float4* __restrict__ q,
    float* __restrict__ dist, double* __restrict__ blockSums,
    unsigned int* __restrict__ ghist)
{
    __shared__ unsigned int lhist[NBINS];
    __shared__ double wsum[4];

    const int tid = threadIdx.x;
    for (int i = tid; i < NBINS; i += 256) lhist[i] = 0u;
    const int lane16 = tid & 15;
    const float4 q4 = q[lane16];
    __syncthreads();

    const int ngroups = GRID1 * 256 / 16;  // 32768 row-groups
    int group = (blockIdx.x * 256 + tid) >> 4;

    float esum = 0.f;
    for (int row = group; row < N_TRAIN; row += ngroups) {
        float4 v = X[row * 16 + lane16];
        float dx = v.x - q4.x;
        float dy = v.y - q4.y;
        float dz = v.z - q4.z;
        float dw = v.w - q4.w;
        float p = dx * dx + dy * dy + dz * dz + dw * dw;
        p += __shfl_xor(p, 1);
        p += __shfl_xor(p, 2);
        p += __shfl_xor(p, 4);
        p += __shfl_xor(p, 8);
        float d = sqrtf(p);
        if (lane16 == 0) {
            dist[row] = d;
            esum += expf(-d);
            int b = (int)(d * BINSCALE);
            b = b < 0 ? 0 : (b > NBINS - 1 ? NBINS - 1 : b);
            atomicAdd(&lhist[b], 1u);
        }
    }

    // block reduction of esum (also serves as the pre-flush barrier)
    double de = (double)esum;
#pragma unroll
    for (int off = 32; off; off >>= 1) de += __shfl_xor(de, off);
    if ((tid & 63) == 0) wsum[tid >> 6] = de;
    __syncthreads();
    if (tid == 0) blockSums[blockIdx.x] = wsum[0] + wsum[1] + wsum[2] + wsum[3];

    // flush local histogram (skip empty bins to cut global atomics)
    for (int i = tid; i < NBINS; i += 256) {
        unsigned int c = lhist[i];
        if (c) atomicAdd(&ghist[i], c);
    }
}

// ---------------------------------------------------------------------------
// Kernel 2: threshold from histogram (wave-parallel chunked scan), then
// compact all sub-threshold candidates. T = smallest bin with cumulative
// >= 32; every true top-32 element has d <= d_32 < (T+1)/16, so the
// candidate set is exact.
// ---------------------------------------------------------------------------
__global__ __launch_bounds__(256) void compact_kernel(
    const float* __restrict__ dist, const unsigned int* __restrict__ ghist,
    unsigned int* __restrict__ candCount,
    float* __restrict__ cand_v, int* __restrict__ cand_i)
{
    __shared__ unsigned int hsh[NBINS];
    __shared__ float thr_sh;

    const int tid = threadIdx.x;
    for (int i = tid; i < NBINS; i += 256) hsh[i] = ghist[i];
    __syncthreads();

    // wave 0: chunked 64-lane inclusive scan to find the threshold bin.
    // Replaces a serial tid==0 scan (~120 dependent LDS loads at ~40+ cyc
    // each) that every block paid before it could start compacting.
    if (tid < 64) {
        unsigned int carry = 0;
        int T = NBINS - 1;
        for (int c = 0; c < NBINS / 64; ++c) {
            unsigned int sc = hsh[c * 64 + tid];
#pragma unroll
            for (int off = 1; off < 64; off <<= 1) {
                unsigned int o = __shfl_up(sc, off);
                if (tid >= off) sc += o;
            }
            unsigned int cum = carry + sc;
            unsigned long long m = __ballot(cum >= KSEL);   // wave-uniform
            if (m != 0ull) { T = c * 64 + (__ffsll(m) - 1); break; }
            carry += __shfl(sc, 63);
        }
        if (tid == 0) thr_sh = (float)(T + 1) / BINSCALE;   // d < thr <=> bin(d) <= T
    }
    __syncthreads();
    const float thr = thr_sh;

    for (int i = blockIdx.x * 256 + tid; i < N_TRAIN; i += GRID2 * 256) {
        float d = dist[i];
        if (d < thr) {
            unsigned int pos = atomicAdd(candCount, 1u);
            if (pos < CAP) { cand_v[pos] = d; cand_i[pos] = i; }
        }
    }
}

// ---------------------------------------------------------------------------
// Kernel 3 (1 block): global S, register-resident top-32 over the candidates
// (wave 0, packed u64 keys, zero barriers in the loop), weights, y-gather.
// Key = (float_bits(d) << 32) | idx: positive-float bits are order-monotone,
// so u64 min == (smallest d, then smallest idx) — matches jax top_k tie order.
// ---------------------------------------------------------------------------
__global__ __launch_bounds__(256) void final_kernel(
    const float* __restrict__ cand_v, const int* __restrict__ cand_i,
    const unsigned int* __restrict__ candCount,
    const double* __restrict__ blockSums,
    const float* __restrict__ y, float* __restrict__ out)
{
    __shared__ double wsum[4];
    __shared__ double Ssh;
    __shared__ unsigned long long topkey[KSEL];
    __shared__ float tw[KSEL];
    __shared__ int   ti[KSEL];
    __shared__ float accsh[4][64];

    const int tid = threadIdx.x;

    // reduce the 2048 per-block denominator partials
    double s = 0.0;
    for (int i = tid; i < GRID1; i += 256) s += blockSums[i];
#pragma unroll
    for (int off = 32; off; off >>= 1) s += __shfl_xor(s, off);
    if ((tid & 63) == 0) wsum[tid >> 6] = s;
    __syncthreads();
    if (tid == 0) Ssh = wsum[0] + wsum[1] + wsum[2] + wsum[3];

    // wave 0: extraction entirely in registers, no barriers
    if (tid < 64) {
        int n = (int)(*candCount);
        if (n > CAP) n = CAP;   // practically unreachable for this data
        unsigned long long key[CAP / 64];
#pragma unroll
        for (int s2 = 0; s2 < CAP / 64; ++s2) {
            int i = s2 * 64 + tid;
            if (i < n) {
                unsigned long long vb = (unsigned long long)__float_as_uint(cand_v[i]);
                key[s2] = (vb << 32) | (unsigned int)cand_i[i];
            } else {
                key[s2] = ~0ULL;
            }
        }
        for (int k = 0; k < KSEL; ++k) {
            unsigned long long m = key[0];
#pragma unroll
            for (int s2 = 1; s2 < CAP / 64; ++s2) m = key[s2] < m ? key[s2] : m;
#pragma unroll
            for (int off = 32; off; off >>= 1) {
                unsigned long long o = __shfl_xor(m, off);
                m = o < m ? o : m;
            }
            if (tid == 0) topkey[k] = m;
            bool done = false;
#pragma unroll
            for (int s2 = 0; s2 < CAP / 64; ++s2) {
                if (!done && key[s2] == m) { key[s2] = ~0ULL; done = true; }
            }
        }
    }
    __syncthreads();

    if (tid < KSEL) {
        unsigned long long kk = topkey[tid];
        float d = __uint_as_float((unsigned int)(kk >> 32));
        ti[tid] = (int)(kk & 0xffffffffu);
        tw[tid] = (float)(exp(-(double)d) / Ssh);
    }
    __syncthreads();

    {
        int kg = tid >> 6, dim = tid & 63;
        float acc = 0.f;
#pragma unroll
        for (int kk2 = 0; kk2 < 8; ++kk2) {
            int k = kg * 8 + kk2;
            acc += tw[k] * y[(long)ti[k] * 64 + dim];
        }
        accsh[kg][dim] = acc;
    }
    __syncthreads();
    if (tid < 64) out[tid] = accsh[0][tid] + accsh[1][tid] + accsh[2][tid] + accsh[3][tid];
}

extern "C" void kernel_launch(void* const* d_in, const int* in_sizes, int n_in,
                              void* d_out, int out_size, void* d_ws, size_t ws_size,
                              hipStream_t stream) {
    const float* X = (const float*)d_in[0];   // [1e6, 64]
    const float* y = (const float*)d_in[1];   // [1e6, 64]
    const float* q = (const float*)d_in[2];   // [64]
    float* out = (float*)d_out;               // [64]

    char* w = (char*)d_ws;
    float*        dist      = (float*)w;                      // 4,000,000 B
    double*       bsums     = (double*)(w + 4000000);         //    16,384 B
    unsigned int* ghist     = (unsigned int*)(w + 4016384);   //     2,048 B
    unsigned int* candCount = (unsigned int*)(w + 4018432);   //         4 B (zeroed with ghist)
    float*        cand_v    = (float*)(w + 4018440);          //     2,048 B
    int*          cand_i    = (int*)(w + 4020488);            //     2,048 B

    // zero histogram + candidate counter (contiguous 2052 bytes)
    hipMemsetAsync(ghist, 0, 2052, stream);

    dist_kernel<<<GRID1, 256, 0, stream>>>((const float4*)X, (const float4*)q,
                                           dist, bsums, ghist);
    compact_kernel<<<GRID2, 256, 0, stream>>>(dist, ghist, candCount, cand_v, cand_i);
    final_kernel<<<1, 256, 0, stream>>>(cand_v, cand_i, candCount, bsums, y, out);
}